// Round 9
// baseline (390.410 us; speedup 1.0000x reference)
//
#include <hip/hip_runtime.h>
#include <hip/hip_bf16.h>
#include <math.h>

#define B_ 8
#define N_ 1024
#define C_ 768
#define H_ 8
#define HD_ 96
#define DFF_ 3072
#define SC2_ 0.14724454f              // (1/sqrt(96)) * log2(e)
#define SH2_ 11.5415602f              // 8 * log2(e)  (constant exp shift)

typedef __attribute__((ext_vector_type(8))) short bf16x8;
typedef __attribute__((ext_vector_type(4))) float f32x4;
typedef __attribute__((ext_vector_type(4))) short sh4;

__device__ __forceinline__ short f2bf(float f){
  __hip_bfloat16 h = __float2bfloat16(f);
  return __builtin_bit_cast(short, h);
}
__device__ __forceinline__ float bf2f(short s){
  unsigned u = ((unsigned)(unsigned short)s) << 16;
  return __builtin_bit_cast(float, u);
}
#define MFMA16(a,b,c) __builtin_amdgcn_mfma_f32_16x16x32_bf16((a),(b),(c),0,0,0)

__device__ __forceinline__ void gload16(const void* g, void* l){
  __builtin_amdgcn_global_load_lds((const __attribute__((address_space(1))) unsigned int*)g,
                                   (__attribute__((address_space(3))) unsigned int*)l, 16, 0, 0);
}

// ---------------- conv 3x3 SAME on 16x16x3 patches -> q bf16 [B,N,C] --------
__global__ void conv_q_kernel(const float* __restrict__ x, const float* __restrict__ w,
                              short* __restrict__ qb){
  int p = blockIdx.x;
  int t = threadIdx.x;
  __shared__ float xs[768];
  __shared__ float ws[81];
  const float* xp = x + (size_t)p * 768;
  xs[t] = xp[t]; xs[t+256] = xp[t+256]; xs[t+512] = xp[t+512];
  if (t < 81) ws[t] = w[t];
  __syncthreads();
  int i = t >> 4, j = t & 15;
  float a0=0.f, a1=0.f, a2=0.f;
  #pragma unroll
  for (int di=0; di<3; ++di){
    int ii = i + di - 1;
    if (ii < 0 || ii > 15) continue;
    #pragma unroll
    for (int dj=0; dj<3; ++dj){
      int jj = j + dj - 1;
      if (jj < 0 || jj > 15) continue;
      const float* cell = &xs[(ii*16+jj)*3];
      const float* wp = &ws[(di*3+dj)*9];
      #pragma unroll
      for (int ci=0; ci<3; ++ci){
        float xv = cell[ci];
        a0 += xv * wp[ci*3+0];
        a1 += xv * wp[ci*3+1];
        a2 += xv * wp[ci*3+2];
      }
    }
  }
  short* qp = qb + (size_t)p*768 + t*3;
  qp[0]=f2bf(a0); qp[1]=f2bf(a1); qp[2]=f2bf(a2);
}

// ---------------- q [B,N,C] bf16 -> Vt [B,C,N] bf16 -------------------------
__global__ void vt_kernel(const short* __restrict__ in, short* __restrict__ out){
  __shared__ short tile[32][33];
  int b = blockIdx.z;
  int c0 = blockIdx.x*32, n0 = blockIdx.y*32;
  int t = threadIdx.x;
  const short* ib = in + (size_t)b*N_*C_;
  short* ob = out + (size_t)b*C_*N_;
  #pragma unroll
  for (int i=0;i<4;i++){
    int idx = i*256+t; int r = idx>>5, cc = idx&31;
    tile[r][cc] = ib[(size_t)(n0+r)*C_ + c0+cc];
  }
  __syncthreads();
  #pragma unroll
  for (int i=0;i<4;i++){
    int idx = i*256+t; int r = idx>>5, cc = idx&31;
    ob[(size_t)(c0+r)*N_ + n0+cc] = tile[cc][r];
  }
}

// ---------------- W [K,Nn] f32 -> Wt [Nn,K] bf16 ----------------------------
__global__ void wtrans_kernel(const float* __restrict__ in, short* __restrict__ out,
                              int K, int Nn){
  __shared__ float tile[32][33];
  int n0 = blockIdx.x*32, k0 = blockIdx.y*32;
  int t = threadIdx.x;
  #pragma unroll
  for (int i=0;i<4;i++){
    int idx=i*256+t; int r=idx>>5, cc=idx&31;
    tile[r][cc] = in[(size_t)(k0+r)*Nn + n0+cc];
  }
  __syncthreads();
  #pragma unroll
  for (int i=0;i<4;i++){
    int idx=i*256+t; int r=idx>>5, cc=idx&31;
    out[(size_t)(n0+r)*K + k0+cc] = f2bf(tile[cc][r]);
  }
}

// ---------------- attention kernel A: P~ = exp2(QK^T*sc - 8), row sums ------
// grid 512 = 32 bh_local x 16 n-tiles; 256 thr = 4 waves x 16 rows.
__global__ __launch_bounds__(256, 2)
void qkexp_kernel(const short* __restrict__ qb, short* __restrict__ Pt,
                  float* __restrict__ lsums, int b0)
{
  __shared__ short Ks[64*104];   // 64 m-rows x 96 (+8 pad)
  int bid = blockIdx.x;
  int bhl = bid >> 4, nt = bid & 15;
  int b = b0 + (bhl >> 3), h = bhl & 7;
  int n0 = nt*64;
  int t = threadIdx.x, w = t>>6, l = t&63, lg = l>>4, lr = l&15;
  const short* qbase = qb + (size_t)b*N_*C_;

  bf16x8 qf[3];
  #pragma unroll
  for (int kc=0;kc<3;++kc)
    qf[kc] = *(const bf16x8*)(qbase + (size_t)(n0 + w*16 + lr)*C_ + h*HD_ + kc*32 + lg*8);

  bf16x8 kreg[3];
  #pragma unroll
  for (int i=0;i<3;++i){
    int id = i*256+t; int r = id/12, c = id%12;
    kreg[i] = *(const bf16x8*)(qbase + (size_t)r*C_ + h*HD_ + c*8);
  }

  float lsum = 0.f;
  short* prow = Pt + ((size_t)bhl*1024 + n0 + w*16 + lr)*1024;

  for (int mt=0; mt<16; ++mt){
    int m0 = mt*64;
    __syncthreads();
    #pragma unroll
    for (int i=0;i<3;++i){
      int id = i*256+t; int r = id/12, c = id%12;
      *(bf16x8*)&Ks[r*104 + c*8] = kreg[i];
    }
    __syncthreads();
    if (mt < 15){
      int m1 = m0 + 64;
      #pragma unroll
      for (int i=0;i<3;++i){
        int id = i*256+t; int r = id/12, c = id%12;
        kreg[i] = *(const bf16x8*)(qbase + (size_t)(m1+r)*C_ + h*HD_ + c*8);
      }
    }
    #pragma unroll
    for (int s=0;s<4;++s){
      f32x4 sacc = (f32x4){0.f,0.f,0.f,0.f};
      bf16x8 kf[3];
      #pragma unroll
      for (int kc=0;kc<3;++kc)
        kf[kc] = *(const bf16x8*)&Ks[(s*16+lr)*104 + kc*32 + lg*8];
      #pragma unroll
      for (int kc=0;kc<3;++kc)
        sacc = MFMA16(kf[kc], qf[kc], sacc);   // rows m, cols n
      sh4 pv;
      #pragma unroll
      for (int r=0;r<4;++r){
        float e = exp2f(sacc[r]*SC2_ - SH2_);
        lsum += e;
        pv[r] = f2bf(e);
      }
      *(sh4*)&prow[m0 + s*16 + lg*4] = pv;
    }
  }
  lsum += __shfl_xor(lsum, 16);
  lsum += __shfl_xor(lsum, 32);
  if (l < 16) lsums[(size_t)bhl*1024 + n0 + w*16 + l] = lsum;
}

// ---------------- attention kernel B: Amix = sum_h wl*P~ + c, out = Amix@V --
__device__ __forceinline__ void load_mix(const short* __restrict__ Pt, int b_local,
                                         int n0, int m0, int t,
                                         const float wl[4][8], float cw, bf16x8 amc[4]){
  #pragma unroll
  for (int i=0;i<4;++i){
    int r = i*32 + (t>>3), mo = t&7;
    const short* p0 = Pt + ((size_t)(b_local*8)*1024 + (size_t)(n0+r))*1024 + m0 + mo*8;
    float pm[8];
    #pragma unroll
    for (int j=0;j<8;++j) pm[j] = cw;
    #pragma unroll
    for (int h=0;h<8;++h){
      bf16x8 ph = *(const bf16x8*)(p0 + (size_t)h*1024*1024);
      #pragma unroll
      for (int j=0;j<8;++j) pm[j] += wl[i][h]*bf2f(ph[j]);
    }
    #pragma unroll
    for (int j=0;j<8;++j) amc[i][j] = f2bf(pm[j]);
  }
}

__global__ __launch_bounds__(256, 2)
void mixpv_kernel(const short* __restrict__ Pt, const float* __restrict__ lsums,
                  const short* __restrict__ vt, const float* __restrict__ rw,
                  const float* __restrict__ rb, const float* __restrict__ bng,
                  const float* __restrict__ bnb, short* __restrict__ out, int b0)
{
  __shared__ short Am[128*68];   // 128 n-rows x 64 m (+4 pad)
  int bid = blockIdx.x;
  int rank = bid>>3;
  int g = rank & 7;
  int p = (bid&7) + ((rank>>3)<<3);      // 0..31
  int b_local = p>>3;
  int n0 = (p&7)*128;
  int b = b0 + b_local;
  int t = threadIdx.x, w = t>>6, l = t&63, lg = l>>4, lr = l&15;

  float bns = bng[g]*rsqrtf(1.001f);
  float cw = rb[g]*bns + bnb[g];
  float wl[4][8];
  #pragma unroll
  for (int i=0;i<4;++i){
    int r = i*32 + (t>>3);
    #pragma unroll
    for (int h=0;h<8;++h)
      wl[i][h] = (rw[g*8+h]*bns) / lsums[(size_t)(b_local*8+h)*1024 + n0 + r];
  }

  f32x4 acc[2][6];
  #pragma unroll
  for (int a=0;a<2;++a)
    #pragma unroll
    for (int nt=0;nt<6;++nt) acc[a][nt] = (f32x4){0.f,0.f,0.f,0.f};

  bf16x8 amc[4];
  load_mix(Pt, b_local, n0, 0, t, wl, cw, amc);
  const short* vbase = vt + (size_t)b*C_*N_ + (size_t)g*HD_*N_;

  for (int mt=0; mt<16; ++mt){
    int m0 = mt*64;
    __syncthreads();
    #pragma unroll
    for (int i=0;i<4;++i){
      int r = i*32 + (t>>3), mo = t&7;
      *(bf16x8*)&Am[r*68 + mo*8] = amc[i];
    }
    __syncthreads();
    if (mt < 15) load_mix(Pt, b_local, n0, m0+64, t, wl, cw, amc);
    #pragma unroll
    for (int kc=0;kc<2;++kc){
      bf16x8 af[2], bfr[6];
      #pragma unroll
      for (int a=0;a<2;++a)
        af[a] = *(const bf16x8*)&Am[(w*32 + a*16 + lr)*68 + kc*32 + lg*8];
      #pragma unroll
      for (int nt=0;nt<6;++nt)
        bfr[nt] = *(const bf16x8*)(vbase + (size_t)(nt*16+lr)*N_ + m0 + kc*32 + lg*8);
      #pragma unroll
      for (int a=0;a<2;++a)
        #pragma unroll
        for (int nt=0;nt<6;++nt)
          acc[a][nt] = MFMA16(af[a], bfr[nt], acc[a][nt]);
    }
  }

  short* obase = out + (size_t)b*N_*C_;
  #pragma unroll
  for (int a=0;a<2;++a)
    #pragma unroll
    for (int nt=0;nt<6;++nt)
      #pragma unroll
      for (int r=0;r<4;++r)
        obase[(size_t)(n0 + w*32 + a*16 + lg*4 + r)*C_ + g*HD_ + nt*16 + lr]
            = f2bf(acc[a][nt][r]);
}

// ---------------- BT-GEMM 128x128, BK=64, counted-vmcnt 2-deep pipeline -----
// C[M,Nn] = A[M,K](bf16) * Bt[Nn,K]^T(bf16); EPI 0: +bias+res -> f32
//                                            EPI 1: +bias, exact GELU -> bf16
// T4 schedule: prologue stages tiles 0,1; loop waits vmcnt(8) (next tile's
// loads STAY in flight across the barrier), raw s_barrier (no drain), compute,
// lgkmcnt(0)+barrier, then stage(t+2) into the just-freed buffer.
template<int EPI>
__global__ __launch_bounds__(256, 2)
void gemm_bt_kernel(const short* __restrict__ A, const short* __restrict__ Bt,
                    const float* __restrict__ bias, const float* __restrict__ res,
                    float* __restrict__ Of, short* __restrict__ Ob,
                    int M, int Nn, int K)
{
  __shared__ __align__(16) char smem[65536];
  short* Sb = (short*)smem;
  int gm = blockIdx.y*128, gn = blockIdx.x*128;
  int tid = threadIdx.x;
  int w = tid>>6, l = tid&63, lg = l>>4, lr = l&15;
  int wr = w>>1, wc = w&1;
  int srow = l>>3;              // 0..7 within 8-row stage block
  int sg = (l&7) ^ srow;        // pre-swizzled source granule (inverse of read swz)

  const short* Ap = A  + (size_t)(gm + w*8 + srow)*K + sg*8;
  const short* Bp = Bt + (size_t)(gn + w*8 + srow)*K + sg*8;

  f32x4 acc[4][4];
  #pragma unroll
  for (int mt=0;mt<4;++mt)
    #pragma unroll
    for (int nt=0;nt<4;++nt) acc[mt][nt] = (f32x4){0.f,0.f,0.f,0.f};

  int nk = K >> 6;

  auto stage = [&](int tt){
    short* dA = Sb + (tt&1)*16384;
    short* dB = dA + 8192;
    int kb = tt<<6;
    #pragma unroll
    for (int j=0;j<4;++j){
      gload16(Ap + (size_t)j*32*K + kb, dA + (j*32 + w*8)*64);
      gload16(Bp + (size_t)j*32*K + kb, dB + (j*32 + w*8)*64);
    }
  };

  stage(0);
  if (nk > 1) stage(1);

  for (int t=0; t<nk; ++t){
    if (t < nk-1) asm volatile("s_waitcnt vmcnt(8)" ::: "memory");
    else          asm volatile("s_waitcnt vmcnt(0)" ::: "memory");
    __builtin_amdgcn_s_barrier();      // tile t fully staged, t+1 still flying
    short* CA = Sb + (t&1)*16384;
    short* CB = CA + 8192;
    #pragma unroll
    for (int kc=0;kc<2;++kc){
      bf16x8 af[4], bfr[4];
      #pragma unroll
      for (int mt=0;mt<4;++mt){
        int row = wr*64+mt*16+lr;
        af[mt] = *(const bf16x8*)&CA[row*64 + (((kc*4+lg)^(lr&7))*8)];
      }
      #pragma unroll
      for (int nt=0;nt<4;++nt){
        int row = wc*64+nt*16+lr;
        bfr[nt] = *(const bf16x8*)&CB[row*64 + (((kc*4+lg)^(lr&7))*8)];
      }
      #pragma unroll
      for (int mt=0;mt<4;++mt)
        #pragma unroll
        for (int nt=0;nt<4;++nt)
          acc[mt][nt] = MFMA16(af[mt], bfr[nt], acc[mt][nt]);
    }
    asm volatile("s_waitcnt lgkmcnt(0)" ::: "memory");
    __builtin_amdgcn_sched_barrier(0);
    __builtin_amdgcn_s_barrier();      // all waves done reading buf[t&1]
    if (t+2 < nk) stage(t+2);
  }

  // ---- epilogue: stage acc in LDS (XOR-swizzled), vector post-process ----
  __builtin_amdgcn_s_barrier();
  float* Cl = (float*)smem;
  #pragma unroll
  for (int mt=0;mt<4;++mt)
    #pragma unroll
    for (int nt=0;nt<4;++nt)
      #pragma unroll
      for (int r=0;r<4;++r){
        int row = wr*64 + mt*16 + lg*4 + r;
        int col = wc*64 + nt*16 + lr;
        Cl[row*128 + (col ^ ((row&7)<<2))] = acc[mt][nt][r];
      }
  __syncthreads();
  #pragma unroll
  for (int seg=0; seg<16; ++seg){
    int row = seg*8 + (tid>>5);
    int col = (tid&31)*4;
    int colp = col ^ ((row&7)<<2);
    f32x4 c = *(f32x4*)&Cl[row*128 + colp];
    float4 bi = *(const float4*)&bias[gn+col];
    size_t goff = (size_t)(gm+row)*Nn + gn + col;
    if (EPI == 0){
      float4 rs = *(const float4*)&res[goff];
      float4 o = { c[0]+bi.x+rs.x, c[1]+bi.y+rs.y, c[2]+bi.z+rs.z, c[3]+bi.w+rs.w };
      *(float4*)&Of[goff] = o;
    } else {
      float v0 = c[0]+bi.x, v1 = c[1]+bi.y, v2 = c[2]+bi.z, v3 = c[3]+bi.w;
      v0 = 0.5f*v0*(1.0f + erff(v0*0.70710678118654752f));
      v1 = 0.5f*v1*(1.0f + erff(v1*0.70710678118654752f));
      v2 = 0.5f*v2*(1.0f + erff(v2*0.70710678118654752f));
      v3 = 0.5f*v3*(1.0f + erff(v3*0.70710678118654752f));
      sh4 ob = { f2bf(v0), f2bf(v1), f2bf(v2), f2bf(v3) };
      *(sh4*)&Ob[goff] = ob;
    }
  }
}

// ---------------- LayerNorm over 768, 1 wave per row ------------------------
template<int WB>
__global__ void ln_kernel(const float* __restrict__ in, const float* __restrict__ gam,
                          const float* __restrict__ bet, float* __restrict__ of,
                          short* __restrict__ ob)
{
  int row = blockIdx.x*4 + (threadIdx.x>>6);
  int l = threadIdx.x & 63;
  const float* ip = in + (size_t)row*C_;
  float v[12];
  #pragma unroll
  for (int i=0;i<3;i++) *(float4*)&v[i*4] = *(const float4*)(ip + i*256 + l*4);
  float s = 0.f;
  #pragma unroll
  for (int i=0;i<12;i++) s += v[i];
  #pragma unroll
  for (int off=1; off<64; off<<=1) s += __shfl_xor(s, off);
  float mu = s * (1.0f/768.0f);
  float q = 0.f;
  #pragma unroll
  for (int i=0;i<12;i++){ float d = v[i]-mu; q += d*d; }
  #pragma unroll
  for (int off=1; off<64; off<<=1) q += __shfl_xor(q, off);
  float rstd = rsqrtf(q*(1.0f/768.0f) + 1e-3f);
  #pragma unroll
  for (int i=0;i<3;i++){
    float4 gv = *(const float4*)(gam + i*256 + l*4);
    float4 bv = *(const float4*)(bet + i*256 + l*4);
    float o0 = (v[i*4+0]-mu)*rstd*gv.x + bv.x;
    float o1 = (v[i*4+1]-mu)*rstd*gv.y + bv.y;
    float o2 = (v[i*4+2]-mu)*rstd*gv.z + bv.z;
    float o3 = (v[i*4+3]-mu)*rstd*gv.w + bv.w;
    float4 ov = {o0,o1,o2,o3};
    *(float4*)(of + (size_t)row*C_ + i*256 + l*4) = ov;
    if (WB){
      sh4 obv = { f2bf(o0), f2bf(o1), f2bf(o2), f2bf(o3) };
      *(sh4*)(ob + (size_t)row*C_ + i*256 + l*4) = obv;
    }
  }
}

extern "C" void kernel_launch(void* const* d_in, const int* in_sizes, int n_in,
                              void* d_out, int out_size, void* d_ws, size_t ws_size,
                              hipStream_t stream)
{
  const float* enc       = (const float*)d_in[0];
  const float* qconv_w   = (const float*)d_in[1];
  const float* reatten_w = (const float*)d_in[2];
  const float* reatten_b = (const float*)d_in[3];
  const float* bn_gamma  = (const float*)d_in[4];
  const float* bn_beta   = (const float*)d_in[5];
  const float* proj_w    = (const float*)d_in[6];
  const float* proj_b    = (const float*)d_in[7];
  const float* ffn_w1    = (const float*)d_in[8];
  const float* ffn_b1    = (const float*)d_in[9];
  const float* ffn_w2    = (const float*)d_in[10];
  const float* ffn_b2    = (const float*)d_in[11];
  const float* ln1_g     = (const float*)d_in[12];
  const float* ln1_b     = (const float*)d_in[13];
  const float* ln2_g     = (const float*)d_in[14];
  const float* ln2_b     = (const float*)d_in[15];
  float* outp = (float*)d_out;

  char* ws = (char*)d_ws;
  short* qbuf  = (short*)(ws);                         // 12.6 MB  q bf16 [B,N,C]
  short* vtbuf = (short*)(ws + 12582912);              // 12.6 MB  Vt bf16 [B,C,N]
  short* atbuf = (short*)(ws + 25165824);              // 12.6 MB  attn out bf16
  short* ptbuf = (short*)(ws + 37748736);              // 67.1 MB  P~ bf16 (half batches; aliased below)
  float* lsums = (float*)(ws + 104857600);             // 128 KB   row sums
  float* ypre  = (float*)(ws + 37748736);              // 25.2 MB  pre-LN f32 (after attn)
  float* x1    = (float*)(ws + 62914560);              // 25.2 MB  LN1 out f32
  short* x1b   = (short*)(ws + 88080384);              // 12.6 MB  LN1 out bf16
  short* hbuf  = (short*)(ws + 100663296);             // 50.3 MB  FFN hidden bf16
  short* wpt   = (short*)(ws + 150994944);             // 1.2 MB   proj_w^T bf16
  short* w1t   = (short*)(ws + 152174592);              // 4.7 MB   ffn_w1^T bf16
  short* w2t   = (short*)(ws + 156893184);             // 4.7 MB   ffn_w2^T bf16

  conv_q_kernel<<<B_*N_, 256, 0, stream>>>(enc, qconv_w, qbuf);
  vt_kernel<<<dim3(C_/32, N_/32, B_), 256, 0, stream>>>(qbuf, vtbuf);
  wtrans_kernel<<<dim3(C_/32,  C_/32), 256, 0, stream>>>(proj_w, wpt, C_,  C_);
  wtrans_kernel<<<dim3(DFF_/32, C_/32), 256, 0, stream>>>(ffn_w1, w1t, C_,  DFF_);
  wtrans_kernel<<<dim3(C_/32, DFF_/32), 256, 0, stream>>>(ffn_w2, w2t, DFF_, C_);

  for (int half=0; half<2; ++half){
    int b0 = half*4;
    qkexp_kernel<<<512, 256, 0, stream>>>(qbuf, ptbuf, lsums, b0);
    mixpv_kernel<<<256, 256, 0, stream>>>(ptbuf, lsums, vtbuf, reatten_w, reatten_b,
                                          bn_gamma, bn_beta, atbuf, b0);
  }

  gemm_bt_kernel<0><<<dim3(C_/128, (B_*N_)/128), 256, 0, stream>>>(
      atbuf, wpt, proj_b, enc, ypre, nullptr, B_*N_, C_, C_);
  ln_kernel<1><<<(B_*N_)/4, 256, 0, stream>>>(ypre, ln1_g, ln1_b, x1, x1b);
  gemm_bt_kernel<1><<<dim3(DFF_/128, (B_*N_)/128), 256, 0, stream>>>(
      x1b, w1t, ffn_b1, nullptr, nullptr, hbuf, B_*N_, DFF_, C_);
  gemm_bt_kernel<0><<<dim3(C_/128, (B_*N_)/128), 256, 0, stream>>>(
      hbuf, w2t, ffn_b2, x1, ypre, nullptr, B_*N_, C_, DFF_);
  ln_kernel<0><<<(B_*N_)/4, 256, 0, stream>>>(ypre, ln2_g, ln2_b, outp, nullptr);
}

// Round 10
// 375.018 us; speedup vs baseline: 1.0410x; 1.0410x over previous
//
#include <hip/hip_runtime.h>
#include <hip/hip_bf16.h>
#include <math.h>

#define B_ 8
#define N_ 1024
#define C_ 768
#define H_ 8
#define HD_ 96
#define DFF_ 3072
#define SC2_ 0.14724454f              // (1/sqrt(96)) * log2(e)
#define SH2_ 11.5415602f              // 8 * log2(e)  (constant exp shift)

typedef __attribute__((ext_vector_type(8))) short bf16x8;
typedef __attribute__((ext_vector_type(4))) float f32x4;
typedef __attribute__((ext_vector_type(4))) short sh4;

__device__ __forceinline__ short f2bf(float f){
  __hip_bfloat16 h = __float2bfloat16(f);
  return __builtin_bit_cast(short, h);
}
__device__ __forceinline__ float bf2f(short s){
  unsigned u = ((unsigned)(unsigned short)s) << 16;
  return __builtin_bit_cast(float, u);
}
#define MFMA16(a,b,c) __builtin_amdgcn_mfma_f32_16x16x32_bf16((a),(b),(c),0,0,0)

__device__ __forceinline__ void gload16(const void* g, void* l){
  __builtin_amdgcn_global_load_lds((const __attribute__((address_space(1))) unsigned int*)g,
                                   (__attribute__((address_space(3))) unsigned int*)l, 16, 0, 0);
}

// logistic-form tanh-GELU: x * sigmoid(2*0.79788456*(x + 0.044715 x^3)) in exp2
__device__ __forceinline__ float gelu_fast(float v){
  float v2 = v*v;
  float t = v*(2.30206086f + 0.10294103f*v2);   // 2*0.79788456*log2(e)*(v+0.044715v^3)
  return v / (1.0f + exp2f(-t));
}

// ---------------- conv 3x3 SAME on 16x16x3 patches -> q bf16 [B,N,C] --------
__global__ void conv_q_kernel(const float* __restrict__ x, const float* __restrict__ w,
                              short* __restrict__ qb){
  int p = blockIdx.x;
  int t = threadIdx.x;
  __shared__ float xs[768];
  __shared__ float ws[81];
  const float* xp = x + (size_t)p * 768;
  xs[t] = xp[t]; xs[t+256] = xp[t+256]; xs[t+512] = xp[t+512];
  if (t < 81) ws[t] = w[t];
  __syncthreads();
  int i = t >> 4, j = t & 15;
  float a0=0.f, a1=0.f, a2=0.f;
  #pragma unroll
  for (int di=0; di<3; ++di){
    int ii = i + di - 1;
    if (ii < 0 || ii > 15) continue;
    #pragma unroll
    for (int dj=0; dj<3; ++dj){
      int jj = j + dj - 1;
      if (jj < 0 || jj > 15) continue;
      const float* cell = &xs[(ii*16+jj)*3];
      const float* wp = &ws[(di*3+dj)*9];
      #pragma unroll
      for (int ci=0; ci<3; ++ci){
        float xv = cell[ci];
        a0 += xv * wp[ci*3+0];
        a1 += xv * wp[ci*3+1];
        a2 += xv * wp[ci*3+2];
      }
    }
  }
  short* qp = qb + (size_t)p*768 + t*3;
  qp[0]=f2bf(a0); qp[1]=f2bf(a1); qp[2]=f2bf(a2);
}

// ---------------- q [B,N,C] bf16 -> Vt [B,C,N] bf16 -------------------------
__global__ void vt_kernel(const short* __restrict__ in, short* __restrict__ out){
  __shared__ short tile[32][33];
  int b = blockIdx.z;
  int c0 = blockIdx.x*32, n0 = blockIdx.y*32;
  int t = threadIdx.x;
  const short* ib = in + (size_t)b*N_*C_;
  short* ob = out + (size_t)b*C_*N_;
  #pragma unroll
  for (int i=0;i<4;i++){
    int idx = i*256+t; int r = idx>>5, cc = idx&31;
    tile[r][cc] = ib[(size_t)(n0+r)*C_ + c0+cc];
  }
  __syncthreads();
  #pragma unroll
  for (int i=0;i<4;i++){
    int idx = i*256+t; int r = idx>>5, cc = idx&31;
    ob[(size_t)(c0+r)*N_ + n0+cc] = tile[cc][r];
  }
}

// ---------------- W [K,Nn] f32 -> Wt [Nn,K] bf16 ----------------------------
__global__ void wtrans_kernel(const float* __restrict__ in, short* __restrict__ out,
                              int K, int Nn){
  __shared__ float tile[32][33];
  int n0 = blockIdx.x*32, k0 = blockIdx.y*32;
  int t = threadIdx.x;
  #pragma unroll
  for (int i=0;i<4;i++){
    int idx=i*256+t; int r=idx>>5, cc=idx&31;
    tile[r][cc] = in[(size_t)(k0+r)*Nn + n0+cc];
  }
  __syncthreads();
  #pragma unroll
  for (int i=0;i<4;i++){
    int idx=i*256+t; int r=idx>>5, cc=idx&31;
    out[(size_t)(n0+r)*K + k0+cc] = f2bf(tile[cc][r]);
  }
}

// ---------------- attention kernel A: P~ = exp2(QK^T*sc - 8), row sums ------
// grid 512 = 32 bh_local x 16 n-tiles; 256 thr = 4 waves x 16 rows.
__global__ __launch_bounds__(256, 2)
void qkexp_kernel(const short* __restrict__ qb, short* __restrict__ Pt,
                  float* __restrict__ lsums, int b0)
{
  __shared__ short Ks[64*104];   // 64 m-rows x 96 (+8 pad)
  int bid = blockIdx.x;
  int bhl = bid >> 4, nt = bid & 15;
  int b = b0 + (bhl >> 3), h = bhl & 7;
  int n0 = nt*64;
  int t = threadIdx.x, w = t>>6, l = t&63, lg = l>>4, lr = l&15;
  const short* qbase = qb + (size_t)b*N_*C_;

  bf16x8 qf[3];
  #pragma unroll
  for (int kc=0;kc<3;++kc)
    qf[kc] = *(const bf16x8*)(qbase + (size_t)(n0 + w*16 + lr)*C_ + h*HD_ + kc*32 + lg*8);

  bf16x8 kreg[3];
  #pragma unroll
  for (int i=0;i<3;++i){
    int id = i*256+t; int r = id/12, c = id%12;
    kreg[i] = *(const bf16x8*)(qbase + (size_t)r*C_ + h*HD_ + c*8);
  }

  float lsum = 0.f;
  short* prow = Pt + ((size_t)bhl*1024 + n0 + w*16 + lr)*1024;

  for (int mt=0; mt<16; ++mt){
    int m0 = mt*64;
    __syncthreads();
    #pragma unroll
    for (int i=0;i<3;++i){
      int id = i*256+t; int r = id/12, c = id%12;
      *(bf16x8*)&Ks[r*104 + c*8] = kreg[i];
    }
    __syncthreads();
    if (mt < 15){
      int m1 = m0 + 64;
      #pragma unroll
      for (int i=0;i<3;++i){
        int id = i*256+t; int r = id/12, c = id%12;
        kreg[i] = *(const bf16x8*)(qbase + (size_t)(m1+r)*C_ + h*HD_ + c*8);
      }
    }
    #pragma unroll
    for (int s=0;s<4;++s){
      f32x4 sacc = (f32x4){0.f,0.f,0.f,0.f};
      bf16x8 kf[3];
      #pragma unroll
      for (int kc=0;kc<3;++kc)
        kf[kc] = *(const bf16x8*)&Ks[(s*16+lr)*104 + kc*32 + lg*8];
      #pragma unroll
      for (int kc=0;kc<3;++kc)
        sacc = MFMA16(kf[kc], qf[kc], sacc);   // rows m, cols n
      sh4 pv;
      #pragma unroll
      for (int r=0;r<4;++r){
        float e = exp2f(sacc[r]*SC2_ - SH2_);
        lsum += e;
        pv[r] = f2bf(e);
      }
      *(sh4*)&prow[m0 + s*16 + lg*4] = pv;
    }
  }
  lsum += __shfl_xor(lsum, 16);
  lsum += __shfl_xor(lsum, 32);
  if (l < 16) lsums[(size_t)bhl*1024 + n0 + w*16 + l] = lsum;
}

// ---------------- attention kernel B: Amix = sum_h wl*P~ + c, out = Amix@V --
__device__ __forceinline__ void load_mix(const short* __restrict__ Pt, int b_local,
                                         int n0, int m0, int t,
                                         const float wl[4][8], float cw, bf16x8 amc[4]){
  #pragma unroll
  for (int i=0;i<4;++i){
    int r = i*32 + (t>>3), mo = t&7;
    const short* p0 = Pt + ((size_t)(b_local*8)*1024 + (size_t)(n0+r))*1024 + m0 + mo*8;
    float pm[8];
    #pragma unroll
    for (int j=0;j<8;++j) pm[j] = cw;
    #pragma unroll
    for (int h=0;h<8;++h){
      bf16x8 ph = *(const bf16x8*)(p0 + (size_t)h*1024*1024);
      #pragma unroll
      for (int j=0;j<8;++j) pm[j] += wl[i][h]*bf2f(ph[j]);
    }
    #pragma unroll
    for (int j=0;j<8;++j) amc[i][j] = f2bf(pm[j]);
  }
}

__global__ __launch_bounds__(256, 2)
void mixpv_kernel(const short* __restrict__ Pt, const float* __restrict__ lsums,
                  const short* __restrict__ vt, const float* __restrict__ rw,
                  const float* __restrict__ rb, const float* __restrict__ bng,
                  const float* __restrict__ bnb, short* __restrict__ out, int b0)
{
  __shared__ short Am[128*68];   // 128 n-rows x 64 m (+4 pad)
  int bid = blockIdx.x;
  int rank = bid>>3;
  int g = rank & 7;
  int p = (bid&7) + ((rank>>3)<<3);      // 0..31
  int b_local = p>>3;
  int n0 = (p&7)*128;
  int b = b0 + b_local;
  int t = threadIdx.x, w = t>>6, l = t&63, lg = l>>4, lr = l&15;

  float bns = bng[g]*rsqrtf(1.001f);
  float cw = rb[g]*bns + bnb[g];
  float wl[4][8];
  #pragma unroll
  for (int i=0;i<4;++i){
    int r = i*32 + (t>>3);
    #pragma unroll
    for (int h=0;h<8;++h)
      wl[i][h] = (rw[g*8+h]*bns) / lsums[(size_t)(b_local*8+h)*1024 + n0 + r];
  }

  f32x4 acc[2][6];
  #pragma unroll
  for (int a=0;a<2;++a)
    #pragma unroll
    for (int nt=0;nt<6;++nt) acc[a][nt] = (f32x4){0.f,0.f,0.f,0.f};

  bf16x8 amc[4];
  load_mix(Pt, b_local, n0, 0, t, wl, cw, amc);
  const short* vbase = vt + (size_t)b*C_*N_ + (size_t)g*HD_*N_;

  for (int mt=0; mt<16; ++mt){
    int m0 = mt*64;
    __syncthreads();
    #pragma unroll
    for (int i=0;i<4;++i){
      int r = i*32 + (t>>3), mo = t&7;
      *(bf16x8*)&Am[r*68 + mo*8] = amc[i];
    }
    __syncthreads();
    if (mt < 15) load_mix(Pt, b_local, n0, m0+64, t, wl, cw, amc);
    #pragma unroll
    for (int kc=0;kc<2;++kc){
      bf16x8 af[2], bfr[6];
      #pragma unroll
      for (int a=0;a<2;++a)
        af[a] = *(const bf16x8*)&Am[(w*32 + a*16 + lr)*68 + kc*32 + lg*8];
      #pragma unroll
      for (int nt=0;nt<6;++nt)
        bfr[nt] = *(const bf16x8*)(vbase + (size_t)(nt*16+lr)*N_ + m0 + kc*32 + lg*8);
      #pragma unroll
      for (int a=0;a<2;++a)
        #pragma unroll
        for (int nt=0;nt<6;++nt)
          acc[a][nt] = MFMA16(af[a], bfr[nt], acc[a][nt]);
    }
  }

  short* obase = out + (size_t)b*N_*C_;
  #pragma unroll
  for (int a=0;a<2;++a)
    #pragma unroll
    for (int nt=0;nt<6;++nt)
      #pragma unroll
      for (int r=0;r<4;++r)
        obase[(size_t)(n0 + w*32 + a*16 + lg*4 + r)*C_ + g*HD_ + nt*16 + lr]
            = f2bf(acc[a][nt][r]);
}

// ---------------- BT-GEMM 128x128, BK=64, m248-v2 schedule ------------------
// stage(t+1) FIRST -> compute buf[t] (setprio around MFMA) -> vmcnt(0)+ONE
// barrier per K-step. XCD-swizzled 1D grid (all grids %8==0).
// EPI 0: +bias+res -> f32;  EPI 1: +bias, tanh-GELU -> bf16
template<int EPI>
__global__ __launch_bounds__(256, 2)
void gemm_bt_kernel(const short* __restrict__ A, const short* __restrict__ Bt,
                    const float* __restrict__ bias, const float* __restrict__ res,
                    float* __restrict__ Of, short* __restrict__ Ob,
                    int M, int Nn, int K, int nxt)
{
  __shared__ __align__(16) char smem[65536];
  short* Sb = (short*)smem;
  // XCD swizzle: HW assigns bid%8 -> XCD; give each XCD a contiguous s-range
  int cpx = gridDim.x >> 3;
  int s = (blockIdx.x & 7)*cpx + (blockIdx.x >> 3);
  int gn = (s % nxt)*128, gm = (s / nxt)*128;
  int tid = threadIdx.x;
  int w = tid>>6, l = tid&63, lg = l>>4, lr = l&15;
  int wr = w>>1, wc = w&1;
  int srow = l>>3;              // 0..7 within 8-row stage block
  int sg = (l&7) ^ srow;        // pre-swizzled source granule (inverse of read swz)

  const short* Ap = A  + (size_t)(gm + w*8 + srow)*K + sg*8;
  const short* Bp = Bt + (size_t)(gn + w*8 + srow)*K + sg*8;

  f32x4 acc[4][4];
  #pragma unroll
  for (int mt=0;mt<4;++mt)
    #pragma unroll
    for (int nt=0;nt<4;++nt) acc[mt][nt] = (f32x4){0.f,0.f,0.f,0.f};

  int nk = K >> 6;

  auto stage = [&](int tt){
    short* dA = Sb + (tt&1)*16384;
    short* dB = dA + 8192;
    int kb = tt<<6;
    #pragma unroll
    for (int j=0;j<4;++j){
      gload16(Ap + (size_t)j*32*K + kb, dA + (j*32 + w*8)*64);
      gload16(Bp + (size_t)j*32*K + kb, dB + (j*32 + w*8)*64);
    }
  };

  // prologue: fill buf0
  stage(0);
  asm volatile("s_waitcnt vmcnt(0)" ::: "memory");
  __builtin_amdgcn_s_barrier();

  for (int t=0; t<nk; ++t){
    if (t+1 < nk) stage(t+1);          // issue BEFORE compute (latency hidden)
    short* CA = Sb + (t&1)*16384;
    short* CB = CA + 8192;
    #pragma unroll
    for (int kc=0;kc<2;++kc){
      bf16x8 af[4], bfr[4];
      #pragma unroll
      for (int mt=0;mt<4;++mt){
        int row = wr*64+mt*16+lr;
        af[mt] = *(const bf16x8*)&CA[row*64 + (((kc*4+lg)^(lr&7))*8)];
      }
      #pragma unroll
      for (int nt=0;nt<4;++nt){
        int row = wc*64+nt*16+lr;
        bfr[nt] = *(const bf16x8*)&CB[row*64 + (((kc*4+lg)^(lr&7))*8)];
      }
      __builtin_amdgcn_s_setprio(1);
      #pragma unroll
      for (int mt=0;mt<4;++mt)
        #pragma unroll
        for (int nt=0;nt<4;++nt)
          acc[mt][nt] = MFMA16(af[mt], bfr[nt], acc[mt][nt]);
      __builtin_amdgcn_s_setprio(0);
    }
    asm volatile("s_waitcnt vmcnt(0)" ::: "memory");   // staged t+1 landed
    __builtin_amdgcn_s_barrier();                      // one barrier per K-step
  }

  // ---- epilogue: stage acc in LDS (XOR-swizzled), vector post-process ----
  float* Cl = (float*)smem;
  #pragma unroll
  for (int mt=0;mt<4;++mt)
    #pragma unroll
    for (int nt=0;nt<4;++nt)
      #pragma unroll
      for (int r=0;r<4;++r){
        int row = wr*64 + mt*16 + lg*4 + r;
        int col = wc*64 + nt*16 + lr;
        Cl[row*128 + (col ^ ((row&7)<<2))] = acc[mt][nt][r];
      }
  __syncthreads();
  #pragma unroll
  for (int seg=0; seg<16; ++seg){
    int row = seg*8 + (tid>>5);
    int col = (tid&31)*4;
    int colp = col ^ ((row&7)<<2);
    f32x4 c = *(f32x4*)&Cl[row*128 + colp];
    float4 bi = *(const float4*)&bias[gn+col];
    size_t goff = (size_t)(gm+row)*Nn + gn + col;
    if (EPI == 0){
      float4 rs = *(const float4*)&res[goff];
      float4 o = { c[0]+bi.x+rs.x, c[1]+bi.y+rs.y, c[2]+bi.z+rs.z, c[3]+bi.w+rs.w };
      *(float4*)&Of[goff] = o;
    } else {
      sh4 ob = { f2bf(gelu_fast(c[0]+bi.x)), f2bf(gelu_fast(c[1]+bi.y)),
                 f2bf(gelu_fast(c[2]+bi.z)), f2bf(gelu_fast(c[3]+bi.w)) };
      *(sh4*)&Ob[goff] = ob;
    }
  }
}

// ---------------- LayerNorm over 768, 1 wave per row ------------------------
template<int WB>
__global__ void ln_kernel(const float* __restrict__ in, const float* __restrict__ gam,
                          const float* __restrict__ bet, float* __restrict__ of,
                          short* __restrict__ ob)
{
  int row = blockIdx.x*4 + (threadIdx.x>>6);
  int l = threadIdx.x & 63;
  const float* ip = in + (size_t)row*C_;
  float v[12];
  #pragma unroll
  for (int i=0;i<3;i++) *(float4*)&v[i*4] = *(const float4*)(ip + i*256 + l*4);
  float s = 0.f;
  #pragma unroll
  for (int i=0;i<12;i++) s += v[i];
  #pragma unroll
  for (int off=1; off<64; off<<=1) s += __shfl_xor(s, off);
  float mu = s * (1.0f/768.0f);
  float q = 0.f;
  #pragma unroll
  for (int i=0;i<12;i++){ float d = v[i]-mu; q += d*d; }
  #pragma unroll
  for (int off=1; off<64; off<<=1) q += __shfl_xor(q, off);
  float rstd = rsqrtf(q*(1.0f/768.0f) + 1e-3f);
  #pragma unroll
  for (int i=0;i<3;i++){
    float4 gv = *(const float4*)(gam + i*256 + l*4);
    float4 bv = *(const float4*)(bet + i*256 + l*4);
    float o0 = (v[i*4+0]-mu)*rstd*gv.x + bv.x;
    float o1 = (v[i*4+1]-mu)*rstd*gv.y + bv.y;
    float o2 = (v[i*4+2]-mu)*rstd*gv.z + bv.z;
    float o3 = (v[i*4+3]-mu)*rstd*gv.w + bv.w;
    float4 ov = {o0,o1,o2,o3};
    *(float4*)(of + (size_t)row*C_ + i*256 + l*4) = ov;
    if (WB){
      sh4 obv = { f2bf(o0), f2bf(o1), f2bf(o2), f2bf(o3) };
      *(sh4*)(ob + (size_t)row*C_ + i*256 + l*4) = obv;
    }
  }
}

extern "C" void kernel_launch(void* const* d_in, const int* in_sizes, int n_in,
                              void* d_out, int out_size, void* d_ws, size_t ws_size,
                              hipStream_t stream)
{
  const float* enc       = (const float*)d_in[0];
  const float* qconv_w   = (const float*)d_in[1];
  const float* reatten_w = (const float*)d_in[2];
  const float* reatten_b = (const float*)d_in[3];
  const float* bn_gamma  = (const float*)d_in[4];
  const float* bn_beta   = (const float*)d_in[5];
  const float* proj_w    = (const float*)d_in[6];
  const float* proj_b    = (const float*)d_in[7];
  const float* ffn_w1    = (const float*)d_in[8];
  const float* ffn_b1    = (const float*)d_in[9];
  const float* ffn_w2    = (const float*)d_in[10];
  const float* ffn_b2    = (const float*)d_in[11];
  const float* ln1_g     = (const float*)d_in[12];
  const float* ln1_b     = (const float*)d_in[13];
  const float* ln2_g     = (const float*)d_in[14];
  const float* ln2_b     = (const float*)d_in[15];
  float* outp = (float*)d_out;

  char* ws = (char*)d_ws;
  short* qbuf  = (short*)(ws);                         // 12.6 MB  q bf16 [B,N,C]
  short* vtbuf = (short*)(ws + 12582912);              // 12.6 MB  Vt bf16 [B,C,N]
  short* atbuf = (short*)(ws + 25165824);              // 12.6 MB  attn out bf16
  short* ptbuf = (short*)(ws + 37748736);              // 67.1 MB  P~ bf16 (half batches; aliased below)
  float* lsums = (float*)(ws + 104857600);             // 128 KB   row sums
  float* ypre  = (float*)(ws + 37748736);              // 25.2 MB  pre-LN f32 (after attn)
  float* x1    = (float*)(ws + 62914560);              // 25.2 MB  LN1 out f32
  short* x1b   = (short*)(ws + 88080384);              // 12.6 MB  LN1 out bf16
  short* hbuf  = (short*)(ws + 100663296);             // 50.3 MB  FFN hidden bf16
  short* wpt   = (short*)(ws + 150994944);             // 1.2 MB   proj_w^T bf16
  short* w1t   = (short*)(ws + 152174592);             // 4.7 MB   ffn_w1^T bf16
  short* w2t   = (short*)(ws + 156893184);             // 4.7 MB   ffn_w2^T bf16

  conv_q_kernel<<<B_*N_, 256, 0, stream>>>(enc, qconv_w, qbuf);
  vt_kernel<<<dim3(C_/32, N_/32, B_), 256, 0, stream>>>(qbuf, vtbuf);
  wtrans_kernel<<<dim3(C_/32,  C_/32), 256, 0, stream>>>(proj_w, wpt, C_,  C_);
  wtrans_kernel<<<dim3(DFF_/32, C_/32), 256, 0, stream>>>(ffn_w1, w1t, C_,  DFF_);
  wtrans_kernel<<<dim3(C_/32, DFF_/32), 256, 0, stream>>>(ffn_w2, w2t, DFF_, C_);

  for (int half=0; half<2; ++half){
    int b0 = half*4;
    qkexp_kernel<<<512, 256, 0, stream>>>(qbuf, ptbuf, lsums, b0);
    mixpv_kernel<<<256, 256, 0, stream>>>(ptbuf, lsums, vtbuf, reatten_w, reatten_b,
                                          bn_gamma, bn_beta, atbuf, b0);
  }

  gemm_bt_kernel<0><<<(C_/128)*((B_*N_)/128), 256, 0, stream>>>(
      atbuf, wpt, proj_b, enc, ypre, nullptr, B_*N_, C_, C_, C_/128);
  ln_kernel<1><<<(B_*N_)/4, 256, 0, stream>>>(ypre, ln1_g, ln1_b, x1, x1b);
  gemm_bt_kernel<1><<<(DFF_/128)*((B_*N_)/128), 256, 0, stream>>>(
      x1b, w1t, ffn_b1, nullptr, nullptr, hbuf, B_*N_, DFF_, C_, DFF_/128);
  gemm_bt_kernel<0><<<(C_/128)*((B_*N_)/128), 256, 0, stream>>>(
      hbuf, w2t, ffn_b2, x1, ypre, nullptr, B_*N_, C_, DFF_, C_/128);
  ln_kernel<0><<<(B_*N_)/4, 256, 0, stream>>>(ypre, ln2_g, ln2_b, outp, nullptr);
}